// Round 6
// baseline (232.879 us; speedup 1.0000x reference)
//
#include <hip/hip_runtime.h>

// Sparsemax over last dim, rows of N=512 fp32 (65536 rows = 32768 pairs).
// Diagnosis r2-r5: all compute restructurings landed at ~80us because the
// kernel is READ-MLP-bound: each wave kept only 4KB of loads in flight.
// This version: depth-2 pair pipeline (12KB reads in flight at peak) over a
// fully unrolled 4-step schedule, + nontemporal stores so output writes
// don't evict the LLC-resident half of the input.
// tau via Newton on f(tau)=sum(max(z-tau,0))-1 warm-started at rowmax-1,
// two rows solved concurrently (ILP=2), counts via ballot+scalar popcount.

typedef float v4f __attribute__((ext_vector_type(4)));

#define ROW_N 512
#define EPL 8  // elements per lane per row

#define DPP_ADD_STEP(v, ctrl, rmask)                                        \
  v += __int_as_float(__builtin_amdgcn_update_dpp(                          \
      0, __float_as_int(v), ctrl, rmask, 0xf, true))

#define DPP_MAX_STEP(v, ctrl, rmask)                                        \
  v = fmaxf(v, __int_as_float(__builtin_amdgcn_update_dpp(                  \
             __float_as_int(v), __float_as_int(v), ctrl, rmask, 0xf, false)))

__device__ inline void wave_sum64_x2(float& u, float& v) {
  DPP_ADD_STEP(u, 0x111, 0xf); DPP_ADD_STEP(v, 0x111, 0xf);
  DPP_ADD_STEP(u, 0x112, 0xf); DPP_ADD_STEP(v, 0x112, 0xf);
  DPP_ADD_STEP(u, 0x114, 0xf); DPP_ADD_STEP(v, 0x114, 0xf);
  DPP_ADD_STEP(u, 0x118, 0xf); DPP_ADD_STEP(v, 0x118, 0xf);
  DPP_ADD_STEP(u, 0x142, 0xa); DPP_ADD_STEP(v, 0x142, 0xa);
  DPP_ADD_STEP(u, 0x143, 0xc); DPP_ADD_STEP(v, 0x143, 0xc);
  u = __int_as_float(__builtin_amdgcn_readlane(__float_as_int(u), 63));
  v = __int_as_float(__builtin_amdgcn_readlane(__float_as_int(v), 63));
}

__device__ inline void wave_max64_x2(float& u, float& v) {
  DPP_MAX_STEP(u, 0x111, 0xf); DPP_MAX_STEP(v, 0x111, 0xf);
  DPP_MAX_STEP(u, 0x112, 0xf); DPP_MAX_STEP(v, 0x112, 0xf);
  DPP_MAX_STEP(u, 0x114, 0xf); DPP_MAX_STEP(v, 0x114, 0xf);
  DPP_MAX_STEP(u, 0x118, 0xf); DPP_MAX_STEP(v, 0x118, 0xf);
  DPP_MAX_STEP(u, 0x142, 0xa); DPP_MAX_STEP(v, 0x142, 0xa);
  DPP_MAX_STEP(u, 0x143, 0xc); DPP_MAX_STEP(v, 0x143, 0xc);
  u = __int_as_float(__builtin_amdgcn_readlane(__float_as_int(u), 63));
  v = __int_as_float(__builtin_amdgcn_readlane(__float_as_int(v), 63));
}

// Solve both rows of one pair held in registers; then nontemporal-store out.
__device__ inline void solve_store(v4f a0, v4f b0, v4f a1, v4f b1,
                                   float* __restrict__ out, int pp, int lane) {
  float z0[EPL], z1[EPL];
#pragma unroll
  for (int i = 0; i < 4; ++i) {
    z0[i] = a0[i]; z0[i + 4] = b0[i];
    z1[i] = a1[i]; z1[i + 4] = b1[i];
  }
  float m0 = fmaxf(fmaxf(fmaxf(z0[0], z0[1]), fmaxf(z0[2], z0[3])),
                   fmaxf(fmaxf(z0[4], z0[5]), fmaxf(z0[6], z0[7])));
  float m1 = fmaxf(fmaxf(fmaxf(z1[0], z1[1]), fmaxf(z1[2], z1[3])),
                   fmaxf(fmaxf(z1[4], z1[5]), fmaxf(z1[6], z1[7])));
  wave_max64_x2(m0, m1);
  // tau* in [m-1, m): the max element alone contributes 1 at tau=m-1.
  float tau0 = m0 - 1.0f, tau1 = m1 - 1.0f;
  int prev0 = -1, prev1 = -1;
  for (int iter = 0; iter < 16; ++iter) {
    float t0[EPL], t1[EPL];
    int k0 = 0, k1 = 0;
#pragma unroll
    for (int i = 0; i < EPL; ++i) {
      bool g0 = z0[i] > tau0;
      bool g1 = z1[i] > tau1;
      t0[i] = g0 ? z0[i] : 0.0f;
      t1[i] = g1 ? z1[i] : 0.0f;
      k0 += (int)__popcll(__ballot(g0));  // scalar pipe
      k1 += (int)__popcll(__ballot(g1));
    }
    float ls0 = ((t0[0] + t0[1]) + (t0[2] + t0[3])) +
                ((t0[4] + t0[5]) + (t0[6] + t0[7]));
    float ls1 = ((t1[0] + t1[1]) + (t1[2] + t1[3])) +
                ((t1[4] + t1[5]) + (t1[6] + t1[7]));
    wave_sum64_x2(ls0, ls1);
    tau0 = (ls0 - 1.0f) * __builtin_amdgcn_rcpf((float)k0);
    tau1 = (ls1 - 1.0f) * __builtin_amdgcn_rcpf((float)k1);
    // Support shrinks monotonically; equal count => equal set => fixed point.
    if (k0 == prev0 && k1 == prev1) break;
    prev0 = k0; prev1 = k1;
  }
  v4f* po = (v4f*)(out + (size_t)pp * 2 * ROW_N);
  v4f o;
  o = (v4f){fmaxf(z0[0] - tau0, 0.0f), fmaxf(z0[1] - tau0, 0.0f),
            fmaxf(z0[2] - tau0, 0.0f), fmaxf(z0[3] - tau0, 0.0f)};
  __builtin_nontemporal_store(o, po + lane);
  o = (v4f){fmaxf(z0[4] - tau0, 0.0f), fmaxf(z0[5] - tau0, 0.0f),
            fmaxf(z0[6] - tau0, 0.0f), fmaxf(z0[7] - tau0, 0.0f)};
  __builtin_nontemporal_store(o, po + lane + 64);
  o = (v4f){fmaxf(z1[0] - tau1, 0.0f), fmaxf(z1[1] - tau1, 0.0f),
            fmaxf(z1[2] - tau1, 0.0f), fmaxf(z1[3] - tau1, 0.0f)};
  __builtin_nontemporal_store(o, po + lane + 128);
  o = (v4f){fmaxf(z1[4] - tau1, 0.0f), fmaxf(z1[5] - tau1, 0.0f),
            fmaxf(z1[6] - tau1, 0.0f), fmaxf(z1[7] - tau1, 0.0f)};
  __builtin_nontemporal_store(o, po + lane + 192);
}

#define LOAD_PAIR(pp, A, B, C, D)                                           \
  do {                                                                      \
    const v4f* _p = (const v4f*)(x + (size_t)(pp) * 2 * ROW_N);             \
    A = _p[lane]; B = _p[lane + 64];                                        \
    C = _p[lane + 128]; D = _p[lane + 192];                                 \
  } while (0)

// Exact-shape kernel: npairs == 4 * nwaves. Depth-2 pair pipeline.
__global__ __launch_bounds__(256) void sparsemax_pipe4(
    const float* __restrict__ x, float* __restrict__ out, int S /*nwaves*/) {
  const int lane = threadIdx.x & 63;
  const int wid = (int)((blockIdx.x * blockDim.x + threadIdx.x) >> 6);
  const int p0 = wid, p1 = wid + S, p2 = wid + 2 * S, p3 = wid + 3 * S;

  v4f A, B, C, D, E, F, G, H, I, J, K, L;
  LOAD_PAIR(p0, A, B, C, D);          // in flight: p0
  LOAD_PAIR(p1, E, F, G, H);          // in flight: p0,p1 (8KB)
  LOAD_PAIR(p2, I, J, K, L);          // in flight: p0,p1,p2 (12KB)
  solve_store(A, B, C, D, out, p0, lane);
  LOAD_PAIR(p3, A, B, C, D);          // refill into p0's registers
  solve_store(E, F, G, H, out, p1, lane);
  solve_store(I, J, K, L, out, p2, lane);
  solve_store(A, B, C, D, out, p3, lane);
}

// Generic fallback (round-5 structure) for any shape.
__global__ __launch_bounds__(256) void sparsemax_generic(
    const float* __restrict__ x, float* __restrict__ out, int npairs) {
  const int lane = threadIdx.x & 63;
  const int wid = (int)((blockIdx.x * blockDim.x + threadIdx.x) >> 6);
  const int nwaves = (int)((gridDim.x * blockDim.x) >> 6);
  for (int pp = wid; pp < npairs; pp += nwaves) {
    v4f A, B, C, D;
    LOAD_PAIR(pp, A, B, C, D);
    solve_store(A, B, C, D, out, pp, lane);
  }
}

extern "C" void kernel_launch(void* const* d_in, const int* in_sizes, int n_in,
                              void* d_out, int out_size, void* d_ws,
                              size_t ws_size, hipStream_t stream) {
  const float* x = (const float*)d_in[0];
  float* out = (float*)d_out;
  const int nrows = in_sizes[0] / ROW_N;
  const int npairs = nrows / 2;  // rows are even (64*1024 rows)
  if (npairs % 4 == 0 && (npairs / 4) % 4 == 0) {
    const int S = npairs / 4;        // waves; 4 pairs per wave
    sparsemax_pipe4<<<S / 4, 256, 0, stream>>>(x, out, S);
  } else {
    sparsemax_generic<<<2048, 256, 0, stream>>>(x, out, npairs);
  }
}